// Round 1
// baseline (106.371 us; speedup 1.0000x reference)
//
#include <hip/hip_runtime.h>

#define BB 64
#define KK 4096
#define DD 512
#define HH 512

// ---------------- Kernel A: qh'[b][h] = b1[h] + sum_d q[b][d] * W1[d][h] ----
// grid: (B) blocks, 512 threads (one h per thread). q row staged in LDS.
__global__ __launch_bounds__(512) void qh_kernel(
    const int* __restrict__ xq, const float* __restrict__ qemb,
    const float* __restrict__ W1, const float* __restrict__ b1,
    float* __restrict__ qh) {
  __shared__ float qrow[DD];
  const int b = blockIdx.x;
  const int row = xq[b];
  const float* qp = qemb + (long)row * DD;
  qrow[threadIdx.x] = qp[threadIdx.x];
  __syncthreads();
  const int h = threadIdx.x;
  float acc = b1[h];
  #pragma unroll 8
  for (int d = 0; d < DD; ++d) {
    acc = fmaf(qrow[d], W1[d * HH + h], acc);
  }
  qh[b * HH + h] = acc;
}

// ---------------- Kernel B: khT[h][k] = sum_d key[k][d] * W1[D+d][h] --------
// 64x64 output tile (h x k), 256 threads, 4x4 per thread, LDS-staged fp32 GEMM.
#define BT_PAD 68
__global__ __launch_bounds__(256) void khT_kernel(
    const float* __restrict__ kemb, const float* __restrict__ W1,
    float* __restrict__ khT) {
  __shared__ float As[32][64];       // d x h
  __shared__ float Bt[32][BT_PAD];   // d x k (padded: 272B rows, 16B aligned)
  const int kb = blockIdx.x * 64;
  const int hb = blockIdx.y * 64;
  const int t  = threadIdx.x;
  const int tx = t & 15;   // k / 4
  const int ty = t >> 4;   // h / 4
  float c[4][4] = {};
  for (int d0 = 0; d0 < DD; d0 += 32) {
    #pragma unroll
    for (int i = 0; i < 8; ++i) {           // stage W1b: 32d x 64h
      int lin = t + i * 256;
      int r = lin >> 6, cc = lin & 63;
      As[r][cc] = W1[(DD + d0 + r) * HH + hb + cc];
    }
    #pragma unroll
    for (int i = 0; i < 8; ++i) {           // stage key tile transposed: 32d x 64k
      int lin = t + i * 256;
      int kk = lin >> 5, dd = lin & 31;
      Bt[dd][kk] = kemb[(long)(kb + kk) * DD + d0 + dd];
    }
    __syncthreads();
    #pragma unroll
    for (int dd = 0; dd < 32; ++dd) {
      float4 a4 = *(const float4*)&As[dd][ty * 4];
      float4 b4 = *(const float4*)&Bt[dd][tx * 4];
      c[0][0] = fmaf(a4.x, b4.x, c[0][0]);
      c[0][1] = fmaf(a4.x, b4.y, c[0][1]);
      c[0][2] = fmaf(a4.x, b4.z, c[0][2]);
      c[0][3] = fmaf(a4.x, b4.w, c[0][3]);
      c[1][0] = fmaf(a4.y, b4.x, c[1][0]);
      c[1][1] = fmaf(a4.y, b4.y, c[1][1]);
      c[1][2] = fmaf(a4.y, b4.z, c[1][2]);
      c[1][3] = fmaf(a4.y, b4.w, c[1][3]);
      c[2][0] = fmaf(a4.z, b4.x, c[2][0]);
      c[2][1] = fmaf(a4.z, b4.y, c[2][1]);
      c[2][2] = fmaf(a4.z, b4.z, c[2][2]);
      c[2][3] = fmaf(a4.z, b4.w, c[2][3]);
      c[3][0] = fmaf(a4.w, b4.x, c[3][0]);
      c[3][1] = fmaf(a4.w, b4.y, c[3][1]);
      c[3][2] = fmaf(a4.w, b4.z, c[3][2]);
      c[3][3] = fmaf(a4.w, b4.w, c[3][3]);
    }
    __syncthreads();
  }
  #pragma unroll
  for (int i = 0; i < 4; ++i) {
    float4 cv = make_float4(c[i][0], c[i][1], c[i][2], c[i][3]);
    *(float4*)&khT[(long)(hb + ty * 4 + i) * KK + kb + tx * 4] = cv;
  }
}

// ---------------- Kernel C: out[b][k] = b2 + sum_h relu(qh'[b][h]+khT[h][k])*w2[h]
// block: 256 threads = 128 k-cols x 2 b-half-groups (4 b each). 256 blocks total.
__global__ __launch_bounds__(256) void logits_kernel(
    const float* __restrict__ qh, const float* __restrict__ khT,
    const float* __restrict__ w2, const float* __restrict__ b2,
    float* __restrict__ out) {
  __shared__ float qs[8][HH];
  __shared__ float w2s[HH];
  const int kb = blockIdx.x * 128;
  const int b0 = blockIdx.y * 8;
  const int t  = threadIdx.x;
  for (int i = t; i < 8 * HH; i += 256) {
    int bb = i >> 9, hh = i & 511;
    qs[bb][hh] = qh[(b0 + bb) * HH + hh];
  }
  for (int i = t; i < HH; i += 256) w2s[i] = w2[i];
  __syncthreads();
  const int k  = kb + (t & 127);
  const int bh = (t >> 7) * 4;   // 0 or 4
  float acc[4] = {0.f, 0.f, 0.f, 0.f};
  #pragma unroll 4
  for (int h = 0; h < HH; ++h) {
    float kv = khT[h * KK + k];
    float w  = w2s[h];
    #pragma unroll
    for (int j = 0; j < 4; ++j) {
      float v = qs[bh + j][h] + kv;
      v = fmaxf(v, 0.f);
      acc[j] = fmaf(v, w, acc[j]);
    }
  }
  const float bias = b2[0];
  #pragma unroll
  for (int j = 0; j < 4; ++j)
    out[(b0 + bh + j) * KK + k] = acc[j] + bias;
}

extern "C" void kernel_launch(void* const* d_in, const int* in_sizes, int n_in,
                              void* d_out, int out_size, void* d_ws, size_t ws_size,
                              hipStream_t stream) {
  const int*   xq   = (const int*)d_in[0];
  const float* qemb = (const float*)d_in[1];
  const float* kemb = (const float*)d_in[2];
  const float* W1   = (const float*)d_in[3];
  const float* b1   = (const float*)d_in[4];
  const float* W2   = (const float*)d_in[5];
  const float* b2   = (const float*)d_in[6];
  float* out = (float*)d_out;

  float* qh  = (float*)d_ws;            // B*H floats
  float* khT = qh + BB * HH;            // H*K floats

  hipLaunchKernelGGL(qh_kernel, dim3(BB), dim3(512), 0, stream,
                     xq, qemb, W1, b1, qh);
  hipLaunchKernelGGL(khT_kernel, dim3(KK / 64, HH / 64), dim3(256), 0, stream,
                     kemb, W1, khT);
  hipLaunchKernelGGL(logits_kernel, dim3(KK / 128, BB / 8), dim3(256), 0, stream,
                     qh, khT, W2, b2, out);
}

// Round 2
// 62.316 us; speedup vs baseline: 1.7070x; 1.7070x over previous
//
#include <hip/hip_runtime.h>

#define BB 64
#define KK 4096
#define DD 512
#define HH 512

typedef __attribute__((ext_vector_type(8))) short bf16x8;
typedef __attribute__((ext_vector_type(4))) float f32x4;

// float -> bf16 bits, round-to-nearest-even
__device__ __forceinline__ unsigned short f2b(float f) {
  unsigned u = __float_as_uint(f);
  unsigned r = u + 0x7fffu + ((u >> 16) & 1u);
  return (unsigned short)(r >> 16);
}

// ---------------- Kernel A: qh'[b][h] = b1[h] + sum_d q[b][d] * W1[d][h] ----
__global__ __launch_bounds__(512) void qh_kernel(
    const int* __restrict__ xq, const float* __restrict__ qemb,
    const float* __restrict__ W1, const float* __restrict__ b1,
    float* __restrict__ qh) {
  __shared__ float qrow[DD];
  const int b = blockIdx.x;
  const int row = xq[b];
  qrow[threadIdx.x] = qemb[(long)row * DD + threadIdx.x];
  __syncthreads();
  const int h = threadIdx.x;
  float acc = b1[h];
  #pragma unroll 8
  for (int d = 0; d < DD; ++d)
    acc = fmaf(qrow[d], W1[d * HH + h], acc);
  qh[b * HH + h] = acc;
}

// ---------------- Kernel T: W1bT[h][d] = bf16(W1[(D+d)*H + h]) -------------
__global__ __launch_bounds__(256) void w1bt_kernel(
    const float* __restrict__ W1, unsigned short* __restrict__ W1bT) {
  __shared__ float tile[32][33];
  const int d0 = blockIdx.x * 32, h0 = blockIdx.y * 32;
  for (int i = threadIdx.x; i < 1024; i += 256) {
    int r = i >> 5, c = i & 31;                    // r: d, c: h
    tile[r][c] = W1[(DD + d0 + r) * HH + h0 + c];  // coalesced over h
  }
  __syncthreads();
  for (int i = threadIdx.x; i < 1024; i += 256) {
    int r = i >> 5, c = i & 31;                    // r: h, c: d
    W1bT[(h0 + r) * DD + d0 + c] = f2b(tile[c][r]); // coalesced over d
  }
}

// ---------------- Kernel B: khT[h][k] = bf16( sum_d W1b[d][h]*kemb[k][d] ) --
// MFMA 16x16x32 bf16. Wave tile: 32h x 64k. Block: 4 waves = 128h x 64k.
// A-frag: lane l holds W1bT[hb + (l&15)][d0 + (l>>4)*8 + i]  (contig 8 bf16)
// B-frag: lane l holds kemb[kb + (l&15)][d0 + (l>>4)*8 + i]  (fp32->bf16)
// D: row=(l>>4)*4+r (h), col=l&15 (k)   [verified layout, learn_hip m89/m91]
__global__ __launch_bounds__(256) void khT_mfma_kernel(
    const float* __restrict__ kemb, const unsigned short* __restrict__ W1bT,
    unsigned short* __restrict__ khT) {
  const int t = threadIdx.x;
  const int l = t & 63, w = t >> 6;
  const int kb = blockIdx.x * 64;
  const int hb = blockIdx.y * 128 + w * 32;
  const int lm = l & 15, lg = l >> 4;
  f32x4 acc[2][4] = {};
  const unsigned short* ap = W1bT + (hb + lm) * DD + lg * 8;
  const float* bp0 = kemb + (long)(kb + lm) * DD + lg * 8;
  for (int d0 = 0; d0 < DD; d0 += 32) {
    bf16x8 a0 = *(const bf16x8*)(ap + d0);
    bf16x8 a1 = *(const bf16x8*)(ap + 16 * DD + d0);
    bf16x8 bfr[4];
    #pragma unroll
    for (int nt = 0; nt < 4; ++nt) {
      const float* bp = bp0 + (long)nt * 16 * DD + d0;
      float4 lo = *(const float4*)bp;
      float4 hi = *(const float4*)(bp + 4);
      bf16x8 bb;
      bb[0] = (short)f2b(lo.x); bb[1] = (short)f2b(lo.y);
      bb[2] = (short)f2b(lo.z); bb[3] = (short)f2b(lo.w);
      bb[4] = (short)f2b(hi.x); bb[5] = (short)f2b(hi.y);
      bb[6] = (short)f2b(hi.z); bb[7] = (short)f2b(hi.w);
      bfr[nt] = bb;
    }
    #pragma unroll
    for (int nt = 0; nt < 4; ++nt) {
      acc[0][nt] = __builtin_amdgcn_mfma_f32_16x16x32_bf16(a0, bfr[nt], acc[0][nt], 0, 0, 0);
      acc[1][nt] = __builtin_amdgcn_mfma_f32_16x16x32_bf16(a1, bfr[nt], acc[1][nt], 0, 0, 0);
    }
  }
  #pragma unroll
  for (int mt = 0; mt < 2; ++mt)
    #pragma unroll
    for (int nt = 0; nt < 4; ++nt)
      #pragma unroll
      for (int r = 0; r < 4; ++r)
        khT[(hb + mt * 16 + lg * 4 + r) * KK + kb + nt * 16 + lm] = f2b(acc[mt][nt][r]);
}

// ---------------- Kernel C: out[b][k] = b2 + sum_h relu(qh'[b][h]+khT[h][k])*w2[h]
// 512 threads: kq=t&31 (32 k-quads = 128 k), hs=(t>>5)&7 (8 h-slices of 64),
// bg=t>>8 (2 groups x 4 b = 8 b). 16 accs/thread; in-block reduce over hs.
__global__ __launch_bounds__(512) void logits2_kernel(
    const float* __restrict__ qh, const unsigned short* __restrict__ khT,
    const float* __restrict__ w2, const float* __restrict__ b2,
    float* __restrict__ out) {
  __shared__ float qs[8][HH];
  __shared__ float w2s[HH];
  __shared__ float part[8][32][17];   // [wave][kq][jb*4+jk], padded
  const int t = threadIdx.x;
  const int kb = blockIdx.x * 128;
  const int b0 = blockIdx.y * 8;
  for (int i = t; i < 8 * HH; i += 512)
    qs[i >> 9][i & 511] = qh[(b0 + (i >> 9)) * HH + (i & 511)];
  w2s[t & 511] = w2[t & 511];
  __syncthreads();
  const int kq = t & 31, hs = (t >> 5) & 7, bg = t >> 8;
  const unsigned short* kp = khT + (hs * 64) * KK + kb + kq * 4;
  float acc[4][4] = {};
  #pragma unroll 4
  for (int i = 0; i < 64; ++i) {
    const int h = hs * 64 + i;
    ushort4 kv = *(const ushort4*)kp; kp += KK;
    float k0 = __uint_as_float((unsigned)kv.x << 16);
    float k1 = __uint_as_float((unsigned)kv.y << 16);
    float k2 = __uint_as_float((unsigned)kv.z << 16);
    float k3 = __uint_as_float((unsigned)kv.w << 16);
    const float wv = w2s[h];
    #pragma unroll
    for (int jb = 0; jb < 4; ++jb) {
      const float q = qs[bg * 4 + jb][h];
      acc[jb][0] = fmaf(fmaxf(q + k0, 0.f), wv, acc[jb][0]);
      acc[jb][1] = fmaf(fmaxf(q + k1, 0.f), wv, acc[jb][1]);
      acc[jb][2] = fmaf(fmaxf(q + k2, 0.f), wv, acc[jb][2]);
      acc[jb][3] = fmaf(fmaxf(q + k3, 0.f), wv, acc[jb][3]);
    }
  }
  // reduce the two h-slices held by each wave (lanes l <-> l^32)
  #pragma unroll
  for (int jb = 0; jb < 4; ++jb)
    #pragma unroll
    for (int jk = 0; jk < 4; ++jk)
      acc[jb][jk] += __shfl_xor(acc[jb][jk], 32);
  const int wid = t >> 6;
  if ((t & 63) < 32) {
    #pragma unroll
    for (int jb = 0; jb < 4; ++jb)
      #pragma unroll
      for (int jk = 0; jk < 4; ++jk)
        part[wid][kq][jb * 4 + jk] = acc[jb][jk];
  }
  __syncthreads();
  // final: sum 4 waves per b-group, add bias, store
  const float bias = b2[0];
  #pragma unroll
  for (int rep = 0; rep < 2; ++rep) {
    int o = t + rep * 512;
    int obg = o >> 9, ojb = (o >> 7) & 3, ojk = (o >> 5) & 3, okq = o & 31;
    float s = bias;
    #pragma unroll
    for (int ww = 0; ww < 4; ++ww)
      s += part[obg * 4 + ww][okq][ojb * 4 + ojk];
    out[(b0 + obg * 4 + ojb) * KK + kb + okq * 4 + ojk] = s;
  }
}

extern "C" void kernel_launch(void* const* d_in, const int* in_sizes, int n_in,
                              void* d_out, int out_size, void* d_ws, size_t ws_size,
                              hipStream_t stream) {
  const int*   xq   = (const int*)d_in[0];
  const float* qemb = (const float*)d_in[1];
  const float* kemb = (const float*)d_in[2];
  const float* W1   = (const float*)d_in[3];
  const float* b1   = (const float*)d_in[4];
  const float* W2   = (const float*)d_in[5];
  const float* b2   = (const float*)d_in[6];
  float* out = (float*)d_out;

  float* qh = (float*)d_ws;                                   // 128 KB
  unsigned short* khT  = (unsigned short*)(qh + BB * HH);     // 4 MB (bf16)
  unsigned short* W1bT = khT + (long)HH * KK;                 // 512 KB (bf16)

  hipLaunchKernelGGL(qh_kernel, dim3(BB), dim3(512), 0, stream,
                     xq, qemb, W1, b1, qh);
  hipLaunchKernelGGL(w1bt_kernel, dim3(16, 16), dim3(256), 0, stream,
                     W1, W1bT);
  hipLaunchKernelGGL(khT_mfma_kernel, dim3(KK / 64, HH / 128), dim3(256), 0, stream,
                     kemb, W1bT, khT);
  hipLaunchKernelGGL(logits2_kernel, dim3(KK / 128, BB / 8), dim3(512), 0, stream,
                     qh, khT, W2, b2, out);
}